// Round 4
// baseline (323.969 us; speedup 1.0000x reference)
//
#include <hip/hip_runtime.h>
#include <hip/hip_cooperative_groups.h>
#include <math.h>

namespace cg = cooperative_groups;

// Problem constants: B=8, C=64, H=W=128, N=16384, E=3, HEADS=16
// ws layout (BYTE offsets). Total need: 20,580,480 bytes.
#define WS_XGP   0           // 16384 f32: per-block channel-sum partials
#define WS_PART  65536       // 655360 f32: per-block cov partials (256 x 2560)
#define WS_COV   2686976     // 32768 f32: full symmetric Cov[b][64][64]
#define WS_XG    2818048     // 512 f32: channel sums
#define WS_LOGIT 2820096     // 24 f32 (padded to 32)
#define WS_MV    2820224     // 98304 f32: attn-folded Wv per (e,b)
#define WS_H     3213440     // 589824 B: H[b][64][576] bf16
#define WS_XT    3803264     // 16777216 B: x_t[b][px][c] bf16

// out layout (float offsets)
#define OUT_HID   8388608
#define OUT_LOGIT 8388736

#define XP 4224      // 66*64 ushorts per conv halo row
#define HP 584       // H LDS pitch (73*8, odd multiple of 8 -> conflict-free)

typedef __attribute__((ext_vector_type(8))) short bf16x8;
typedef __attribute__((ext_vector_type(4))) float f32x4;

__device__ inline unsigned short f2bf(float f) {
    union { float f; unsigned int u; } v; v.f = f;
    return (unsigned short)((v.u + 0x7FFFu + ((v.u >> 16) & 1u)) >> 16);
}
__device__ inline float bf2f(unsigned short h) {
    union { unsigned int u; float f; } v; v.u = ((unsigned int)h) << 16;
    return v.f;
}

// ===========================================================================
// Single cooperative kernel: 256 blocks x 512 threads, 5 grid syncs.
// LDS is a 159232-byte union re-purposed per phase (1 block/CU).
// ===========================================================================
__global__ __launch_bounds__(512) void fused_kernel(
    const float* __restrict__ x, const float* __restrict__ hidden,
    const float* __restrict__ qkv_w, const float* __restrict__ dw_w,
    const float* __restrict__ proj_w, const float* __restrict__ temp,
    const float* __restrict__ r1w, const float* __restrict__ r1b,
    const float* __restrict__ r3w, const float* __restrict__ r3b,
    float* __restrict__ ws, float* __restrict__ out)
{
    __shared__ __align__(16) char smem[159232];
    cg::grid_group grid = cg::this_grid();
    const int t = threadIdx.x;
    const int blk = blockIdx.x;
    const int w = t >> 6, l = t & 63;

    float* const XGPp = (float*)((char*)ws + WS_XGP);
    float* const PARTp = (float*)((char*)ws + WS_PART);
    float* const COVp = (float*)((char*)ws + WS_COV);
    float* const XGp  = (float*)((char*)ws + WS_XG);
    float* const LOGp = (float*)((char*)ws + WS_LOGIT);
    float* const MVp  = (float*)((char*)ws + WS_MV);
    unsigned short* const Hp  = (unsigned short*)((char*)ws + WS_H);
    unsigned short* const XTp = (unsigned short*)((char*)ws + WS_XT);

    // ===== P1: cov partials (MFMA Gram, deterministic) + x_t transpose =====
    {
        unsigned short* xl = (unsigned short*)smem;       // [64][520] bf16
        float* red = (float*)(smem + 66560);              // [8][2560]
        float* xgl = (float*)(smem + 148480);             // [8][64]
        const int b = blk >> 5, chunk = blk & 31;
        const float* xb = x + ((size_t)b << 20) + (chunk << 9);

        // stage 512px x 64ch fp32 -> bf16 (coalesced float4)
        for (int i = 0; i < 16; ++i) {
            const int idx = (i << 9) + t;
            const int c = idx >> 7, u = idx & 127;
            const float4 v = *(const float4*)(xb + ((size_t)c << 14) + (u << 2));
            unsigned long long pk = (unsigned long long)f2bf(v.x)
                                  | ((unsigned long long)f2bf(v.y) << 16)
                                  | ((unsigned long long)f2bf(v.z) << 32)
                                  | ((unsigned long long)f2bf(v.w) << 48);
            *(unsigned long long*)&xl[c * 520 + (u << 2)] = pk;
        }
        __syncthreads();

        // channel-sum partials (rotated start -> bank spread)
        {
            const int c = t & 63, g = t >> 6;
            float s = 0.f;
            for (int i = 0; i < 64; ++i)
                s += bf2f(xl[c * 520 + (g << 6) + ((i + c) & 63)]);
            xgl[(g << 6) + c] = s;
        }

        // Gram MFMA: wave w covers px [w*64, w*64+64), A-frag == B-frag
        f32x4 acc[10];
        const f32x4 fz = {0.f, 0.f, 0.f, 0.f};
        #pragma unroll
        for (int q = 0; q < 10; ++q) acc[q] = fz;
        const int lane_a = (l & 15) * 520 + (l >> 4) * 8;
        #pragma unroll
        for (int ks = 0; ks < 2; ++ks) {
            const int p0 = (w << 6) + (ks << 5);
            bf16x8 fr[4];
            #pragma unroll
            for (int mi = 0; mi < 4; ++mi)
                fr[mi] = *(const bf16x8*)&xl[mi * 16 * 520 + p0 + lane_a];
            int q = 0;
            #pragma unroll
            for (int mi = 0; mi < 4; ++mi)
                #pragma unroll
                for (int ni = mi; ni < 4; ++ni) {
                    acc[q] = __builtin_amdgcn_mfma_f32_16x16x32_bf16(fr[mi], fr[ni], acc[q], 0, 0, 0);
                    ++q;
                }
        }

        // x_t write: [b][px][c] bf16 (hides under MFMA latency)
        {
            unsigned short* xtw = XTp + ((size_t)b << 20)
                                + ((size_t)((chunk << 9) + t) << 6);
            #pragma unroll
            for (int i = 0; i < 8; ++i) {
                bf16x8 v;
                #pragma unroll
                for (int k = 0; k < 8; ++k) v[k] = (short)xl[(i * 8 + k) * 520 + t];
                *(bf16x8*)&xtw[i << 3] = v;
            }
        }

        // per-wave frags -> LDS, block-reduce, write partials (no atomics)
        #pragma unroll
        for (int q = 0; q < 10; ++q)
            #pragma unroll
            for (int j = 0; j < 4; ++j)
                red[w * 2560 + q * 256 + ((l >> 4) * 4 + j) * 16 + (l & 15)] = acc[q][j];
        __syncthreads();
        for (int i = t; i < 2560; i += 512) {
            float s = 0.f;
            #pragma unroll
            for (int wv = 0; wv < 8; ++wv) s += red[wv * 2560 + i];
            PARTp[(size_t)blk * 2560 + i] = s;
        }
        if (t < 64) {
            float s = 0.f;
            #pragma unroll
            for (int g = 0; g < 8; ++g) s += xgl[(g << 6) + t];
            XGPp[(blk << 6) + t] = s;
        }
    }
    grid.sync();

    // ===== P2: reduce partials -> full symmetric Cov + XG =====
    if (blk < 80) {
        const int b = blk / 10, q = blk - b * 10;
        int mi, ni;
        if (q < 4)      { mi = 0; ni = q; }
        else if (q < 7) { mi = 1; ni = q - 2; }
        else if (q < 9) { mi = 2; ni = q - 5; }
        else            { mi = 3; ni = 3; }
        if (t < 256) {
            float s = 0.f;
            for (int k = 0; k < 32; ++k)
                s += PARTp[(size_t)(b * 32 + k) * 2560 + q * 256 + t];
            const int r = mi * 16 + (t >> 4), c = ni * 16 + (t & 15);
            COVp[b * 4096 + r * 64 + c] = s;
            if (mi != ni) COVp[b * 4096 + c * 64 + r] = s;
        } else if (q == 0 && t < 320) {
            const int c = t - 256;
            float s = 0.f;
            for (int k = 0; k < 32; ++k) s += XGPp[((b * 32 + k) << 6) + c];
            XGp[(b << 6) + c] = s;
        }
    }
    grid.sync();

    // ===== P3: routing MLP (block 0, fp32 exact) =====
    if (blk == 0) {
        float* hn = (float*)smem;
        if (t < 128) {
            const int b = t >> 4, j = t & 15;
            const float* xg = XGp + (b << 6);
            float s = r1b[j];
            for (int c = 0; c < 64; ++c) s += r1w[j*80 + c] * (xg[c] * (1.0f/16384.0f));
            for (int k = 0; k < 16; ++k) s += r1w[j*80 + 64 + k] * hidden[b*16 + k];
            float g = 0.5f * s * (1.0f + erff(s * 0.70710678118654752440f));
            hn[t] = g;
            out[OUT_HID + t] = g;
        }
        __syncthreads();
        if (t < 24) {
            const int b = t / 3, e = t - b * 3;
            float s = r3b[e];
            for (int j = 0; j < 16; ++j) s += r3w[e*16 + j] * hn[b*16 + j];
            s = fmaxf(s, 0.0f);
            LOGp[t] = s;
            out[OUT_LOGIT + t] = s;
        }
    }
    grid.sync();

    // ===== P4: attention finalize -> Mv (24 blocks) =====
    if (blk < 24) {
        const int e = blk >> 3, bb = blk & 7;
        const float lg = LOGp[bb * 3 + e];
        if (lg > 0.0f) {
            float* Wl  = (float*)smem;              // [192*65]
            float* Cv  = (float*)(smem + 49920);    // [64*65]
            float* TQ  = (float*)(smem + 66560);
            float* TK  = (float*)(smem + 83200);
            float* qkb = (float*)(smem + 99840);
            float* qqb = (float*)(smem + 100864);
            float* kkb = (float*)(smem + 101120);
            float* atl = (float*)(smem + 101376);

            for (int idx = t; idx < 12288; idx += 512)
                Wl[(idx >> 6) * 65 + (idx & 63)] = qkv_w[e * 12288 + idx];
            for (int idx = t; idx < 4096; idx += 512)
                Cv[(idx >> 6) * 65 + (idx & 63)] = COVp[bb * 4096 + idx];
            __syncthreads();

            {   // TQ = Wq*Cov, TK = Wk*Cov (r = t>>3, 8 cols each)
                const int r = t >> 3, cq = (t & 7) << 3;
                float aq[8], ak[8];
                #pragma unroll
                for (int i = 0; i < 8; ++i) { aq[i] = 0.f; ak[i] = 0.f; }
                for (int c1 = 0; c1 < 64; ++c1) {
                    const float wq = Wl[r * 65 + c1];
                    const float wk = Wl[(64 + r) * 65 + c1];
                    #pragma unroll
                    for (int i = 0; i < 8; ++i) {
                        const float cv = Cv[c1 * 65 + cq + i];
                        aq[i] += wq * cv; ak[i] += wk * cv;
                    }
                }
                #pragma unroll
                for (int i = 0; i < 8; ++i) { TQ[r*65 + cq + i] = aq[i]; TK[r*65 + cq + i] = ak[i]; }
            }
            __syncthreads();

            if (t < 384) {   // per-head gram entries
                const int h = t / 24, u = t - h * 24;
                float s = 0.f;
                if (u < 16) {
                    const int i = u >> 2, j = u & 3;
                    const float* tq = &TQ[(4*h + i) * 65];
                    const float* wk = &Wl[(64 + 4*h + j) * 65];
                    for (int c = 0; c < 64; ++c) s += tq[c] * wk[c];
                    qkb[h * 16 + u] = s;
                } else if (u < 20) {
                    const int i = u - 16;
                    const float* tq = &TQ[(4*h + i) * 65];
                    const float* wq = &Wl[(4*h + i) * 65];
                    for (int c = 0; c < 64; ++c) s += tq[c] * wq[c];
                    qqb[h * 4 + i] = s;
                } else {
                    const int j = u - 20;
                    const float* tk = &TK[(4*h + j) * 65];
                    const float* wk = &Wl[(64 + 4*h + j) * 65];
                    for (int c = 0; c < 64; ++c) s += tk[c] * wk[c];
                    kkb[h * 4 + j] = s;
                }
            }
            __syncthreads();

            if (t < 64) {    // softmax over j (4-wide)
                const int h = t >> 2, i = t & 3;
                const float tp = temp[e * 16 + h];
                const float rq = 1.0f / fmaxf(sqrtf(qqb[h*4 + i]), 1e-12f);
                float lq[4];
                #pragma unroll
                for (int j = 0; j < 4; ++j) {
                    const float rk = 1.0f / fmaxf(sqrtf(kkb[h*4 + j]), 1e-12f);
                    lq[j] = qkb[h*16 + i*4 + j] * rq * rk * tp;
                }
                const float m = fmaxf(fmaxf(lq[0], lq[1]), fmaxf(lq[2], lq[3]));
                float ex[4]; float s = 0.f;
                #pragma unroll
                for (int j = 0; j < 4; ++j) { ex[j] = expf(lq[j] - m); s += ex[j]; }
                const float inv = 1.0f / s;
                #pragma unroll
                for (int j = 0; j < 4; ++j) atl[h*16 + i*4 + j] = ex[j] * inv;
            }
            __syncthreads();

            float* mv = MVp + (size_t)blk * 4096;
            for (int idx = t; idx < 4096; idx += 512) {
                const int o = idx >> 6, c = idx & 63;
                const int h = o >> 2, ii = o & 3;
                float s = 0.f;
                #pragma unroll
                for (int j = 0; j < 4; ++j)
                    s += atl[h*16 + ii*4 + j] * Wl[(128 + 4*h + j) * 65 + c];
                mv[idx] = s;
            }
        }
    }
    grid.sync();

    // ===== P5: fold logit*proj*dw(tap)*Mv -> H bf16 (72 blocks) =====
    if (blk < 72) {
        float* Pl = (float*)smem;             // [64*65]
        float* Ml = (float*)(smem + 16640);   // [64*65]
        const int b = blk / 9, tap = blk - b * 9;
        const int o = t >> 3, c8 = (t & 7) << 3;
        float s[8];
        #pragma unroll
        for (int i = 0; i < 8; ++i) s[i] = 0.f;
        for (int e = 0; e < 3; ++e) {
            const float lg = LOGp[b * 3 + e];
            __syncthreads();
            if (lg > 0.f) {
                for (int idx = t; idx < 4096; idx += 512) {
                    const int oo = idx >> 6, mm = idx & 63;
                    Pl[oo * 65 + mm] = proj_w[e * 4096 + idx] * dw_w[e * 576 + mm * 9 + tap] * lg;
                    Ml[oo * 65 + mm] = MVp[(size_t)(e * 8 + b) * 4096 + idx];
                }
                __syncthreads();
                for (int m = 0; m < 64; ++m) {
                    const float wv = Pl[o * 65 + m];
                    const float* mr = &Ml[m * 65 + c8];
                    #pragma unroll
                    for (int i = 0; i < 8; ++i) s[i] += wv * mr[i];
                }
            }
        }
        unsigned short* hrow = Hp + (size_t)((b * 64 + o) * 576) + tap * 64 + c8;
        #pragma unroll
        for (int i = 0; i < 8; ++i) hrow[i] = f2bf(s[i]);
    }
    grid.sync();

    // ===== P6: implicit-GEMM 3x3 conv from x_t (coalesced bf16 staging) =====
    {
        unsigned short* xl = (unsigned short*)smem;            // [10][XP]
        unsigned short* hl = (unsigned short*)(smem + 84480);  // [64][HP]
        const int b = blk >> 5;
        const int tile = blk & 31;
        const int ty = tile >> 1, tx = tile & 1;
        const int y0 = ty << 3, x0 = tx << 6;
        const unsigned short* xt = XTp + ((size_t)b << 20);

        // x halo: per row one contiguous 8448B segment; swizzled LDS dest
        for (int rr = w; rr < 10; rr += 8) {
            const int gy = y0 - 1 + rr;
            const bool yok = ((unsigned)gy < 128u);
            for (int u = l; u < 528; u += 64) {
                const int col = u >> 3, j = u & 7;
                const int gx = x0 - 1 + col;
                bf16x8 v = {0, 0, 0, 0, 0, 0, 0, 0};
                if (yok && ((unsigned)gx < 128u))
                    v = *(const bf16x8*)&xt[((size_t)((gy << 7) + gx) << 6) + (j << 3)];
                *(bf16x8*)&xl[rr * XP + (col << 6) + ((j ^ (col & 7)) << 3)] = v;
            }
        }
        // H: conflict-free 16B-granular staging
        {
            const unsigned short* hg = Hp + (size_t)b * 36864;
            const int o = t >> 3, u = t & 7;
            #pragma unroll
            for (int i = 0; i < 9; ++i) {
                const int cu = u + (i << 3);
                *(bf16x8*)&hl[o * HP + (cu << 3)] = *(const bf16x8*)&hg[o * 576 + (cu << 3)];
            }
        }
        __syncthreads();

        f32x4 acc[4][4];
        const f32x4 fz = {0.f, 0.f, 0.f, 0.f};
        #pragma unroll
        for (int mi = 0; mi < 4; ++mi)
            #pragma unroll
            for (int f = 0; f < 4; ++f) acc[mi][f] = fz;

        const int aoff = (l & 15) * HP + (l >> 4) * 8;
        const int bcol = (l & 15) * 64;
        int su8[3][2];
        #pragma unroll
        for (int dxi = 0; dxi < 3; ++dxi)
            #pragma unroll
            for (int s = 0; s < 2; ++s)
                su8[dxi][s] = ((s * 4 + (l >> 4)) ^ (((l & 15) + dxi) & 7)) << 3;

        #pragma unroll
        for (int tap = 0; tap < 9; ++tap) {
            const int dy = tap / 3 - 1;
            const int dxi = tap % 3;
            const int hr = w + 1 + dy;
            #pragma unroll
            for (int s = 0; s < 2; ++s) {
                const int k0 = tap * 64 + s * 32;
                bf16x8 af[4], bfr[4];
                #pragma unroll
                for (int mi = 0; mi < 4; ++mi)
                    af[mi] = *(const bf16x8*)&hl[mi * 16 * HP + k0 + aoff];
                #pragma unroll
                for (int f = 0; f < 4; ++f)
                    bfr[f] = *(const bf16x8*)&xl[hr * XP + (f * 16 + dxi) * 64 + bcol + su8[dxi][s]];
                #pragma unroll
                for (int mi = 0; mi < 4; ++mi)
                    #pragma unroll
                    for (int f = 0; f < 4; ++f)
                        acc[mi][f] = __builtin_amdgcn_mfma_f32_16x16x32_bf16(af[mi], bfr[f], acc[mi][f], 0, 0, 0);
            }
        }

        // epilogue: D col=lane&15 (pixel), row=(lane>>4)*4+j (channel)
        const int gy = y0 + w;
        float* ob = out + ((size_t)b << 20) + (gy << 7) + x0;
        const int orow = (l >> 4) << 2;
        const int ocol = l & 15;
        #pragma unroll
        for (int mi = 0; mi < 4; ++mi)
            #pragma unroll
            for (int f = 0; f < 4; ++f)
                #pragma unroll
                for (int j = 0; j < 4; ++j)
                    ob[((size_t)(mi * 16 + orow + j) << 14) + f * 16 + ocol] = acc[mi][f][j];
    }
}

// ---------------------------------------------------------------------------
extern "C" void kernel_launch(void* const* d_in, const int* in_sizes, int n_in,
                              void* d_out, int out_size, void* d_ws, size_t ws_size,
                              hipStream_t stream) {
    const float* x      = (const float*)d_in[0];
    const float* hidden = (const float*)d_in[1];
    const float* qkv_w  = (const float*)d_in[2];
    const float* dw_w   = (const float*)d_in[3];
    const float* proj_w = (const float*)d_in[4];
    const float* temp   = (const float*)d_in[5];
    const float* r1w    = (const float*)d_in[6];
    const float* r1b    = (const float*)d_in[7];
    const float* r3w    = (const float*)d_in[8];
    const float* r3b    = (const float*)d_in[9];
    float* out = (float*)d_out;
    float* ws  = (float*)d_ws;

    void* args[] = { (void*)&x, (void*)&hidden, (void*)&qkv_w, (void*)&dw_w,
                     (void*)&proj_w, (void*)&temp, (void*)&r1w, (void*)&r1b,
                     (void*)&r3w, (void*)&r3b, (void*)&ws, (void*)&out };
    hipLaunchCooperativeKernel((const void*)fused_kernel, dim3(256), dim3(512),
                               args, 0, stream);
}

// Round 7
// 177.157 us; speedup vs baseline: 1.8287x; 1.8287x over previous
//
#include <hip/hip_runtime.h>
#include <math.h>

// Problem constants: B=8, C=64, H=W=128, N=16384, E=3, HEADS=16

// ws layout (float offsets unless noted)
#define OFF_XG    0          // 512  (B*C channel sums, atomically accumulated)
#define OFF_COV   512        // 8*64*64 = 32768 (per-batch covariance, upper-tri written, atomic)
#define OFF_LOGIT 33280      // 24   (B*E relu gate)
#define OFF_MV    33312      // 3*8*64*64 = 98304 fp32 (attn-folded Wv per (e,b))
#define OFF_H_BYTES  526464  // byte offset: H[b][64][576] bf16 = 589824 bytes
#define OFF_XT_BYTES 1116288 // byte offset: x_t[b][px][c] bf16 = 16777216 bytes
// total ws need: 17,893,504 bytes

// out layout (float offsets)
#define OUT_HID   8388608
#define OUT_LOGIT 8388736

#define XP 4224      // 66*64 ushorts per conv halo row
#define HP 584       // H LDS pitch in ushorts (73*8; 292 dwords, %32=4 -> 2-way max on A-reads)

typedef __attribute__((ext_vector_type(8))) short bf16x8;
typedef __attribute__((ext_vector_type(4))) float f32x4;

__device__ inline unsigned short f2bf(float f) {
    union { float f; unsigned int u; } v; v.f = f;
    return (unsigned short)((v.u + 0x7FFFu + ((v.u >> 16) & 1u)) >> 16);
}
__device__ inline float bf2f(unsigned short h) {
    union { unsigned int u; float f; } v; v.u = ((unsigned int)h) << 16;
    return v.f;
}

// ---------------------------------------------------------------------------
// Kernel 1: MFMA Gram: Cov[b] = X X^T (upper-tri blocks) + channel sums
//           + x_t transpose emit ([b][px][c] bf16) for the conv kernel.
// grid 256 = 8 b x 32 chunks (512 px each), block 256 (4 waves).
// ---------------------------------------------------------------------------
__global__ __launch_bounds__(256) void cov_kernel(const float* __restrict__ x,
                                                  float* __restrict__ ws) {
    __shared__ unsigned short xl[64 * 520];   // [c][512 px], pitch 520
    const int t = threadIdx.x;
    const int w = t >> 6, l = t & 63;
    const int b = blockIdx.x >> 5;
    const int chunk = blockIdx.x & 31;
    const float* xb = x + ((size_t)b << 20) + (chunk << 9);

    // stage 512px x 64ch fp32 -> bf16, coalesced float4
    for (int i = 0; i < 32; ++i) {
        const int idx = i * 256 + t;
        const int c = idx >> 7, u = idx & 127;
        const float4 v = *(const float4*)(xb + ((size_t)c << 14) + (u << 2));
        unsigned long long pk = (unsigned long long)f2bf(v.x)
                              | ((unsigned long long)f2bf(v.y) << 16)
                              | ((unsigned long long)f2bf(v.z) << 32)
                              | ((unsigned long long)f2bf(v.w) << 48);
        *(unsigned long long*)&xl[c * 520 + (u << 2)] = pk;
    }
    __syncthreads();

    // channel partial sums for x_global (sequential order, round-3-exact)
    {
        const int c = t & 63, q = t >> 6;
        float s = 0.f;
        for (int u = 0; u < 16; ++u) {
            const unsigned short* p = &xl[c * 520 + q * 128 + u * 8];
            #pragma unroll
            for (int j = 0; j < 8; ++j) s += bf2f(p[j]);
        }
        atomicAdd(ws + OFF_XG + b * 64 + c, s);
    }

    f32x4 acc[10];
    const f32x4 fz = {0.f, 0.f, 0.f, 0.f};
    #pragma unroll
    for (int q = 0; q < 10; ++q) acc[q] = fz;

    const int lane_a = (l & 15) * 520 + (l >> 4) * 8;
    #pragma unroll
    for (int ks = 0; ks < 4; ++ks) {
        const int p0 = w * 128 + ks * 32;
        bf16x8 fr[4];
        #pragma unroll
        for (int mi = 0; mi < 4; ++mi)
            fr[mi] = *(const bf16x8*)&xl[mi * 16 * 520 + p0 + lane_a];
        int q = 0;
        #pragma unroll
        for (int mi = 0; mi < 4; ++mi)
            #pragma unroll
            for (int ni = mi; ni < 4; ++ni) {
                acc[q] = __builtin_amdgcn_mfma_f32_16x16x32_bf16(fr[mi], fr[ni], acc[q], 0, 0, 0);
                ++q;
            }
    }

    // x_t emit: [b][px][c] bf16 (reads xl before it is re-purposed below)
    {
        unsigned short* xtw = (unsigned short*)((char*)ws + OFF_XT_BYTES)
                            + ((size_t)b << 20) + ((size_t)(chunk << 9) << 6);
        for (int p = t; p < 512; p += 256) {
            #pragma unroll
            for (int i = 0; i < 8; ++i) {
                bf16x8 v;
                #pragma unroll
                for (int k = 0; k < 8; ++k) v[k] = (short)xl[(i * 8 + k) * 520 + p];
                *(bf16x8*)&xtw[((size_t)p << 6) + (i << 3)] = v;
            }
        }
    }
    __syncthreads();

    // cross-wave reduce in LDS (alias xl), then atomics (upper blocks only)
    float* red = (float*)xl;
    #pragma unroll
    for (int q = 0; q < 10; ++q)
        #pragma unroll
        for (int j = 0; j < 4; ++j)
            red[w * 2560 + q * 256 + ((l >> 4) * 4 + j) * 16 + (l & 15)] = acc[q][j];
    __syncthreads();

    const int MI[10] = {0,0,0,0,1,1,1,2,2,3};
    const int NI[10] = {0,1,2,3,1,2,3,2,3,3};
    #pragma unroll
    for (int k = 0; k < 10; ++k) {
        const int i = k * 256 + t;
        const float s = red[i] + red[2560 + i] + red[5120 + i] + red[7680 + i];
        const int r = MI[k] * 16 + (t >> 4), c = NI[k] * 16 + (t & 15);
        atomicAdd(ws + OFF_COV + b * 4096 + r * 64 + c, s);
    }
}

// ---------------------------------------------------------------------------
// Kernel 2: routing MLP. 1 block, 128 threads. (fp32 exact path)
// ---------------------------------------------------------------------------
__global__ __launch_bounds__(128) void route_kernel(const float* __restrict__ hidden,
        const float* __restrict__ r1w, const float* __restrict__ r1b,
        const float* __restrict__ r3w, const float* __restrict__ r3b,
        float* __restrict__ ws, float* __restrict__ out) {
    __shared__ float hn[128];
    const int t = threadIdx.x;
    {
        const int b = t >> 4, j = t & 15;
        const float* xg = ws + OFF_XG + b * 64;
        float s = r1b[j];
        for (int c = 0; c < 64; ++c) s += r1w[j*80 + c] * (xg[c] * (1.0f/16384.0f));
        for (int k = 0; k < 16; ++k) s += r1w[j*80 + 64 + k] * hidden[b*16 + k];
        float g = 0.5f * s * (1.0f + erff(s * 0.70710678118654752440f));
        hn[t] = g;
        out[OUT_HID + t] = g;
    }
    __syncthreads();
    if (t < 24) {
        const int b = t / 3, e = t - b * 3;
        float s = r3b[e];
        for (int j = 0; j < 16; ++j) s += r3w[e*16 + j] * hn[b*16 + j];
        s = fmaxf(s, 0.0f);
        ws[OFF_LOGIT + t] = s;
        out[OUT_LOGIT + t] = s;
    }
}

// ---------------------------------------------------------------------------
// Kernel 3: attention finalize. grid 24 = (e,b), block 256.
// Per-head 4x4 softmax attn from Cov (symmetric read), folds into Wv -> Mv.
// ---------------------------------------------------------------------------
__global__ __launch_bounds__(256) void attn_kernel(const float* __restrict__ qkv_w,
        const float* __restrict__ temp, float* __restrict__ ws) {
    __shared__ float Wl[192 * 65];
    __shared__ float Cv[64 * 65];
    __shared__ float TQ[64 * 65];
    __shared__ float TK[64 * 65];
    __shared__ float qkb[256];
    __shared__ float qqb[64];
    __shared__ float kkb[64];
    __shared__ float atl[256];
    const int t = threadIdx.x;
    const int e = blockIdx.x >> 3, b = blockIdx.x & 7;
    const float lg = ws[OFF_LOGIT + b * 3 + e];
    if (!(lg > 0.0f)) return;              // gated off: contribution is exactly 0

    for (int idx = t; idx < 12288; idx += 256)
        Wl[(idx >> 6) * 65 + (idx & 63)] = qkv_w[e * 12288 + idx];
    for (int idx = t; idx < 4096; idx += 256) {
        const int r = idx >> 6, c = idx & 63;
        const int rr = r < c ? r : c, cc = r < c ? c : r;   // cov is upper-tri
        Cv[r * 65 + c] = ws[OFF_COV + b * 4096 + rr * 64 + cc];
    }
    __syncthreads();

    {   // TQ = Wq*Cov, TK = Wk*Cov
        const int r = t >> 2, cq = (t & 3) << 4;
        float aq[16], ak[16];
        #pragma unroll
        for (int i = 0; i < 16; ++i) { aq[i] = 0.f; ak[i] = 0.f; }
        for (int c1 = 0; c1 < 64; ++c1) {
            float wq = Wl[r * 65 + c1];
            float wk = Wl[(64 + r) * 65 + c1];
            #pragma unroll
            for (int i = 0; i < 16; ++i) {
                float cv = Cv[c1 * 65 + cq + i];
                aq[i] += wq * cv; ak[i] += wk * cv;
            }
        }
        #pragma unroll
        for (int i = 0; i < 16; ++i) { TQ[r*65 + cq + i] = aq[i]; TK[r*65 + cq + i] = ak[i]; }
    }
    __syncthreads();

    for (int idx = t; idx < 384; idx += 256) {   // per-head gram entries
        const int h = idx / 24, u = idx - h * 24;
        float s = 0.f;
        if (u < 16) {
            const int i = u >> 2, j = u & 3;
            const float* tq = &TQ[(4*h + i) * 65];
            const float* wk = &Wl[(64 + 4*h + j) * 65];
            for (int c = 0; c < 64; ++c) s += tq[c] * wk[c];
            qkb[h * 16 + u] = s;
        } else if (u < 20) {
            const int i = u - 16;
            const float* tq = &TQ[(4*h + i) * 65];
            const float* wq = &Wl[(4*h + i) * 65];
            for (int c = 0; c < 64; ++c) s += tq[c] * wq[c];
            qqb[h * 4 + i] = s;
        } else {
            const int j = u - 20;
            const float* tk = &TK[(4*h + j) * 65];
            const float* wk = &Wl[(64 + 4*h + j) * 65];
            for (int c = 0; c < 64; ++c) s += tk[c] * wk[c];
            kkb[h * 4 + j] = s;
        }
    }
    __syncthreads();

    if (t < 64) {                           // softmax over j (4-wide)
        const int h = t >> 2, i = t & 3;
        const float tp = temp[e * 16 + h];
        const float rq = 1.0f / fmaxf(sqrtf(qqb[h*4 + i]), 1e-12f);
        float lq[4];
        #pragma unroll
        for (int j = 0; j < 4; ++j) {
            float rk = 1.0f / fmaxf(sqrtf(kkb[h*4 + j]), 1e-12f);
            lq[j] = qkb[h*16 + i*4 + j] * rq * rk * tp;
        }
        float m = fmaxf(fmaxf(lq[0], lq[1]), fmaxf(lq[2], lq[3]));
        float ex[4]; float s = 0.f;
        #pragma unroll
        for (int j = 0; j < 4; ++j) { ex[j] = expf(lq[j] - m); s += ex[j]; }
        float inv = 1.0f / s;
        #pragma unroll
        for (int j = 0; j < 4; ++j) atl[h*16 + i*4 + j] = ex[j] * inv;
    }
    __syncthreads();

    // Mv[o][c] = sum_j attn[h(o)][o%4][j] * Wv[4h+j][c]
    float* mv = ws + OFF_MV + (size_t)blockIdx.x * 4096;
    for (int idx = t; idx < 4096; idx += 256) {
        const int o = idx >> 6, c = idx & 63;
        const int h = o >> 2, ii = o & 3;
        float s = 0.f;
        #pragma unroll
        for (int j = 0; j < 4; ++j)
            s += atl[h*16 + ii*4 + j] * Wl[(128 + 4*h + j) * 65 + c];
        mv[idx] = s;
    }
}

// ---------------------------------------------------------------------------
// Kernel 3.5: fold logit*proj*dw(tap)*Mv -> H[b][64][tap*64+c] bf16.
// grid 72 = 8 b x 9 taps, block 256. Zero when no expert active.
// ---------------------------------------------------------------------------
__global__ __launch_bounds__(256) void hbuild_kernel(const float* __restrict__ dw_w,
        const float* __restrict__ proj_w, float* __restrict__ ws) {
    __shared__ float Pl[64 * 65];
    __shared__ float Ml[64 * 65];
    const int t = threadIdx.x;
    const int b = blockIdx.x / 9, tap = blockIdx.x - b * 9;
    const int o = t >> 2, c4 = (t & 3) << 4;
    float s[16];
    #pragma unroll
    for (int i = 0; i < 16; ++i) s[i] = 0.f;
    for (int e = 0; e < 3; ++e) {
        const float lg = ws[OFF_LOGIT + b * 3 + e];
        __syncthreads();
        if (lg > 0.f) {
            for (int idx = t; idx < 4096; idx += 256) {
                const int oo = idx >> 6, mm = idx & 63;
                Pl[oo * 65 + mm] = proj_w[e * 4096 + idx] * dw_w[e * 576 + mm * 9 + tap] * lg;
                Ml[oo * 65 + mm] = ws[OFF_MV + (size_t)(e * 8 + b) * 4096 + idx];
            }
            __syncthreads();
            for (int m = 0; m < 64; ++m) {
                const float wv = Pl[o * 65 + m];
                const float* mr = &Ml[m * 65 + c4];
                #pragma unroll
                for (int i = 0; i < 16; ++i) s[i] += wv * mr[i];
            }
        }
    }
    unsigned short* Hg = (unsigned short*)((char*)ws + OFF_H_BYTES);
    unsigned short* hrow = Hg + (size_t)(b * 64 + o) * 576 + tap * 64 + c4;
    #pragma unroll
    for (int i = 0; i < 16; ++i) hrow[i] = f2bf(s[i]);
}

// ---------------------------------------------------------------------------
// Kernel 4: implicit-GEMM 3x3 conv:  out[b] = sum_tap H[b,tap] @ shift(x[b])
// grid 256 = 8 b x 16 ytiles x 2 xtiles, block 512 (8 waves).
// Staging from x_t: contiguous 1KB/instr b128 loads, conflict-free LDS writes.
// K-loop / epilogue byte-identical to the round-3-verified version.
// ---------------------------------------------------------------------------
__global__ __launch_bounds__(512, 2) void conv_kernel(const float* __restrict__ ws_ro,
        float* __restrict__ out) {
    __shared__ unsigned short xl[10 * XP];     // 84480 B
    __shared__ unsigned short hl[64 * HP];     // 74752 B
    const int t = threadIdx.x;
    const int w = t >> 6, l = t & 63;
    const int bx = blockIdx.x;
    const int b = bx >> 5;
    const int tile = bx & 31;
    const int ty = tile >> 1, tx = tile & 1;
    const int y0 = ty << 3, x0 = tx << 6;
    const unsigned short* xt = (const unsigned short*)((const char*)ws_ro + OFF_XT_BYTES)
                             + ((size_t)b << 20);

    // ---- stage x halo from x_t: per instr 64 lanes = 1KB contiguous src,
    //      swizzled-but-128B-grouped LDS dest (0 conflicts) ----
    for (int rr = w; rr < 10; rr += 8) {
        const int gy = y0 - 1 + rr;
        const bool yok = ((unsigned)gy < 128u);
        for (int u = l; u < 528; u += 64) {
            const int col = u >> 3, j = u & 7;
            const int gx = x0 - 1 + col;
            bf16x8 v = {0, 0, 0, 0, 0, 0, 0, 0};
            if (yok && ((unsigned)gx < 128u))
                v = *(const bf16x8*)&xt[((size_t)((gy << 7) + gx) << 6) + (j << 3)];
            *(bf16x8*)&xl[rr * XP + (col << 6) + ((j ^ (col & 7)) << 3)] = v;
        }
    }
    // ---- stage H[b]: wave w stages rows 8w..8w+7, contiguous per row ----
    {
        const unsigned short* hg = (const unsigned short*)((const char*)ws_ro + OFF_H_BYTES)
                                 + (size_t)b * 36864;
        #pragma unroll
        for (int r = 0; r < 8; ++r) {
            const int row = (w << 3) + r;
            for (int u = l; u < 72; u += 64)
                *(bf16x8*)&hl[row * HP + (u << 3)] = *(const bf16x8*)&hg[row * 576 + (u << 3)];
        }
    }
    __syncthreads();

    f32x4 acc[4][4];
    const f32x4 fz = {0.f, 0.f, 0.f, 0.f};
    #pragma unroll
    for (int mi = 0; mi < 4; ++mi)
        #pragma unroll
        for (int f = 0; f < 4; ++f) acc[mi][f] = fz;

    const int aoff = (l & 15) * HP + (l >> 4) * 8;
    const int bcol = (l & 15) * 64;
    int su8[3][2];                         // swizzled unit offset per (dx+1, s)
    #pragma unroll
    for (int dxi = 0; dxi < 3; ++dxi)
        #pragma unroll
        for (int s = 0; s < 2; ++s)
            su8[dxi][s] = ((s * 4 + (l >> 4)) ^ (((l & 15) + dxi) & 7)) << 3;

    #pragma unroll
    for (int tap = 0; tap < 9; ++tap) {
        const int dy = tap / 3 - 1;
        const int dxi = tap % 3;           // dx + 1
        const int hr = w + 1 + dy;
        #pragma unroll
        for (int s = 0; s < 2; ++s) {
            const int k0 = tap * 64 + s * 32;
            bf16x8 af[4], bfr[4];
            #pragma unroll
            for (int mi = 0; mi < 4; ++mi)
                af[mi] = *(const bf16x8*)&hl[mi * 16 * HP + k0 + aoff];
            #pragma unroll
            for (int f = 0; f < 4; ++f)
                bfr[f] = *(const bf16x8*)&xl[hr * XP + (f * 16 + dxi) * 64 + bcol + su8[dxi][s]];
            #pragma unroll
            for (int mi = 0; mi < 4; ++mi)
                #pragma unroll
                for (int f = 0; f < 4; ++f)
                    acc[mi][f] = __builtin_amdgcn_mfma_f32_16x16x32_bf16(af[mi], bfr[f], acc[mi][f], 0, 0, 0);
        }
    }

    // ---- epilogue: D layout col=lane&15 (pixel), row=(lane>>4)*4+j (channel)
    const int gy = y0 + w;
    float* ob = out + ((size_t)b << 20) + (gy << 7) + x0;
    const int orow = (l >> 4) << 2;
    const int ocol = l & 15;
    #pragma unroll
    for (int mi = 0; mi < 4; ++mi)
        #pragma unroll
        for (int f = 0; f < 4; ++f)
            #pragma unroll
            for (int j = 0; j < 4; ++j)
                ob[((size_t)(mi * 16 + orow + j) << 14) + f * 16 + ocol] = acc[mi][f][j];
}

// ---------------------------------------------------------------------------
extern "C" void kernel_launch(void* const* d_in, const int* in_sizes, int n_in,
                              void* d_out, int out_size, void* d_ws, size_t ws_size,
                              hipStream_t stream) {
    const float* x      = (const float*)d_in[0];
    const float* hidden = (const float*)d_in[1];
    const float* qkv_w  = (const float*)d_in[2];
    const float* dw_w   = (const float*)d_in[3];
    const float* proj_w = (const float*)d_in[4];
    const float* temp   = (const float*)d_in[5];
    const float* r1w    = (const float*)d_in[6];
    const float* r1b    = (const float*)d_in[7];
    const float* r3w    = (const float*)d_in[8];
    const float* r3b    = (const float*)d_in[9];
    float* out = (float*)d_out;
    float* ws  = (float*)d_ws;

    // zero the atomic-accumulated regions (ws is poisoned 0xAA before each call)
    hipMemsetAsync(ws, 0, (size_t)(512 + 32768) * sizeof(float), stream);

    cov_kernel   <<<dim3(256), dim3(256), 0, stream>>>(x, ws);
    route_kernel <<<dim3(1),   dim3(128), 0, stream>>>(hidden, r1w, r1b, r3w, r3b, ws, out);
    attn_kernel  <<<dim3(24),  dim3(256), 0, stream>>>(qkv_w, temp, ws);
    hbuild_kernel<<<dim3(72),  dim3(256), 0, stream>>>(dw_w, proj_w, ws);
    conv_kernel  <<<dim3(256), dim3(512), 0, stream>>>(ws, out);
}

// Round 8
// 176.794 us; speedup vs baseline: 1.8325x; 1.0021x over previous
//
#include <hip/hip_runtime.h>
#include <math.h>

// Problem constants: B=8, C=64, H=W=128, N=16384, E=3, HEADS=16

// ws layout (float offsets unless noted)
#define OFF_PART  0          // 655360 f32: per-block cov partials (256 blk x 2560)
#define OFF_XGP   655360     // 16384 f32: per-block channel-sum partials (256 x 64)
#define OFF_LOGIT 671744     // 24 f32 (padded 32)
#define OFF_MV    671776     // 98304 f32: attn-folded Wv per (e,b)
#define OFF_H_BYTES  3080320 // byte offset: H[b][64][576] bf16 = 589824 bytes
#define OFF_XT_BYTES 3670144 // byte offset: x_t[b][px][c] bf16 = 16777216 bytes
// total ws need: 20,447,360 bytes

// out layout (float offsets)
#define OUT_HID   8388608
#define OUT_LOGIT 8388736

#define XP 4224      // 66*64 ushorts per conv halo row
#define HP 584       // H LDS pitch in ushorts (73*8)

typedef __attribute__((ext_vector_type(8))) short bf16x8;
typedef __attribute__((ext_vector_type(4))) float f32x4;

__device__ inline unsigned short f2bf(float f) {
    union { float f; unsigned int u; } v; v.f = f;
    return (unsigned short)((v.u + 0x7FFFu + ((v.u >> 16) & 1u)) >> 16);
}
__device__ inline float bf2f(unsigned short h) {
    union { unsigned int u; float f; } v; v.u = ((unsigned int)h) << 16;
    return v.f;
}

// ---------------------------------------------------------------------------
// Kernel 1: MFMA Gram partials + channel-sum partials + x_t emit.
// grid 256 = 8 b x 32 chunks (512 px each), block 256 (4 waves).
// Deterministic: no atomics, no pre-zeroing needed.
// ---------------------------------------------------------------------------
__global__ __launch_bounds__(256) void cov_kernel(const float* __restrict__ x,
                                                  float* __restrict__ ws) {
    __shared__ unsigned short xl[64 * 520];   // [c][512 px], pitch 520
    __shared__ float xgq[256];                // 4 q-quarter partials x 64 ch
    const int t = threadIdx.x;
    const int w = t >> 6, l = t & 63;
    const int b = blockIdx.x >> 5;
    const int chunk = blockIdx.x & 31;
    const float* xb = x + ((size_t)b << 20) + (chunk << 9);

    // stage 512px x 64ch fp32 -> bf16, coalesced float4
    for (int i = 0; i < 32; ++i) {
        const int idx = i * 256 + t;
        const int c = idx >> 7, u = idx & 127;
        const float4 v = *(const float4*)(xb + ((size_t)c << 14) + (u << 2));
        unsigned long long pk = (unsigned long long)f2bf(v.x)
                              | ((unsigned long long)f2bf(v.y) << 16)
                              | ((unsigned long long)f2bf(v.z) << 32)
                              | ((unsigned long long)f2bf(v.w) << 48);
        *(unsigned long long*)&xl[c * 520 + (u << 2)] = pk;
    }
    __syncthreads();

    // channel partial sums for x_global (sequential per quarter, as verified)
    {
        const int c = t & 63, q = t >> 6;
        float s = 0.f;
        for (int u = 0; u < 16; ++u) {
            const unsigned short* p = &xl[c * 520 + q * 128 + u * 8];
            #pragma unroll
            for (int j = 0; j < 8; ++j) s += bf2f(p[j]);
        }
        xgq[q * 64 + c] = s;
    }

    f32x4 acc[10];
    const f32x4 fz = {0.f, 0.f, 0.f, 0.f};
    #pragma unroll
    for (int q = 0; q < 10; ++q) acc[q] = fz;

    const int lane_a = (l & 15) * 520 + (l >> 4) * 8;
    #pragma unroll
    for (int ks = 0; ks < 4; ++ks) {
        const int p0 = w * 128 + ks * 32;
        bf16x8 fr[4];
        #pragma unroll
        for (int mi = 0; mi < 4; ++mi)
            fr[mi] = *(const bf16x8*)&xl[mi * 16 * 520 + p0 + lane_a];
        int q = 0;
        #pragma unroll
        for (int mi = 0; mi < 4; ++mi)
            #pragma unroll
            for (int ni = mi; ni < 4; ++ni) {
                acc[q] = __builtin_amdgcn_mfma_f32_16x16x32_bf16(fr[mi], fr[ni], acc[q], 0, 0, 0);
                ++q;
            }
    }

    // x_t emit: [b][px][c] bf16 (reads xl before it is re-purposed below)
    {
        unsigned short* xtw = (unsigned short*)((char*)ws + OFF_XT_BYTES)
                            + ((size_t)b << 20) + ((size_t)(chunk << 9) << 6);
        for (int p = t; p < 512; p += 256) {
            #pragma unroll
            for (int i = 0; i < 8; ++i) {
                bf16x8 v;
                #pragma unroll
                for (int k = 0; k < 8; ++k) v[k] = (short)xl[(i * 8 + k) * 520 + p];
                *(bf16x8*)&xtw[((size_t)p << 6) + (i << 3)] = v;
            }
        }
    }
    __syncthreads();

    // cross-wave reduce in LDS (alias xl), write per-block partials
    float* red = (float*)xl;
    #pragma unroll
    for (int q = 0; q < 10; ++q)
        #pragma unroll
        for (int j = 0; j < 4; ++j)
            red[w * 2560 + q * 256 + ((l >> 4) * 4 + j) * 16 + (l & 15)] = acc[q][j];
    __syncthreads();

    float* part = ws + OFF_PART + (size_t)blockIdx.x * 2560;
    for (int i = t; i < 2560; i += 256)
        part[i] = (red[i] + red[2560 + i]) + (red[5120 + i] + red[7680 + i]);
    if (t < 64)
        ws[OFF_XGP + blockIdx.x * 64 + t] =
            (xgq[t] + xgq[64 + t]) + (xgq[128 + t] + xgq[192 + t]);
}

// ---------------------------------------------------------------------------
// Kernel 2: attention finalize with inline routing + partial reduce.
// grid 24 = (e,b), block 256. Reduces cov/xg partials -> LDS, computes the
// routing MLP per-block (deterministic, redundant across e; e==0 writes the
// hid/logit outputs), then per-head 4x4 softmax attn -> Mv.
// ---------------------------------------------------------------------------
__global__ __launch_bounds__(256) void attn_kernel(const float* __restrict__ qkv_w,
        const float* __restrict__ temp, const float* __restrict__ hidden,
        const float* __restrict__ r1w, const float* __restrict__ r1b,
        const float* __restrict__ r3w, const float* __restrict__ r3b,
        float* __restrict__ ws, float* __restrict__ out) {
    __shared__ float Wl[192 * 65];
    __shared__ float Cv[64 * 65];
    __shared__ float TQ[64 * 65];
    __shared__ float TK[64 * 65];
    __shared__ float qkb[256];
    __shared__ float qqb[64];
    __shared__ float kkb[64];
    __shared__ float atl[256];
    __shared__ float xg[64];
    __shared__ float hn[16];
    __shared__ float lgl[3];
    const int t = threadIdx.x;
    const int e = blockIdx.x >> 3, b = blockIdx.x & 7;

    // ---- xg reduce (fixed k order) ----
    if (t < 64) {
        const float* xgp = ws + OFF_XGP + (b * 32) * 64;
        float s = 0.f;
        for (int k = 0; k < 32; ++k) s += xgp[k * 64 + t];
        xg[t] = s;
    }
    __syncthreads();
    // ---- routing MLP (fp32 exact; redundant per e, deterministic) ----
    if (t < 16) {
        float s = r1b[t];
        for (int c = 0; c < 64; ++c) s += r1w[t*80 + c] * (xg[c] * (1.0f/16384.0f));
        for (int k = 0; k < 16; ++k) s += r1w[t*80 + 64 + k] * hidden[b*16 + k];
        float g = 0.5f * s * (1.0f + erff(s * 0.70710678118654752440f));
        hn[t] = g;
        if (e == 0) out[OUT_HID + b * 16 + t] = g;
    }
    __syncthreads();
    if (t < 3) {
        float s = r3b[t];
        for (int j = 0; j < 16; ++j) s += r3w[t*16 + j] * hn[j];
        s = fmaxf(s, 0.0f);
        lgl[t] = s;
        if (e == 0) { ws[OFF_LOGIT + b * 3 + t] = s; out[OUT_LOGIT + b * 3 + t] = s; }
    }
    __syncthreads();
    const float lg = lgl[e];
    if (!(lg > 0.0f)) return;              // gated off: contribution is exactly 0

    // ---- stage W, reduce cov partials -> full symmetric Cv in LDS ----
    for (int idx = t; idx < 12288; idx += 256)
        Wl[(idx >> 6) * 65 + (idx & 63)] = qkv_w[e * 12288 + idx];
    {
        const int MI[10] = {0,0,0,0,1,1,1,2,2,3};
        const int NI[10] = {0,1,2,3,1,2,3,2,3,3};
        const float* part = ws + OFF_PART + (size_t)(b * 32) * 2560;
        for (int idx = t; idx < 2560; idx += 256) {
            float s = 0.f;
            for (int k = 0; k < 32; ++k) s += part[(size_t)k * 2560 + idx];
            const int q = idx >> 8, i = idx & 255;
            const int r = MI[q] * 16 + (i >> 4), c = NI[q] * 16 + (i & 15);
            Cv[r * 65 + c] = s;
            Cv[c * 65 + r] = s;
        }
    }
    __syncthreads();

    {   // TQ = Wq*Cov, TK = Wk*Cov
        const int r = t >> 2, cq = (t & 3) << 4;
        float aq[16], ak[16];
        #pragma unroll
        for (int i = 0; i < 16; ++i) { aq[i] = 0.f; ak[i] = 0.f; }
        for (int c1 = 0; c1 < 64; ++c1) {
            float wq = Wl[r * 65 + c1];
            float wk = Wl[(64 + r) * 65 + c1];
            #pragma unroll
            for (int i = 0; i < 16; ++i) {
                float cv = Cv[c1 * 65 + cq + i];
                aq[i] += wq * cv; ak[i] += wk * cv;
            }
        }
        #pragma unroll
        for (int i = 0; i < 16; ++i) { TQ[r*65 + cq + i] = aq[i]; TK[r*65 + cq + i] = ak[i]; }
    }
    __syncthreads();

    for (int idx = t; idx < 384; idx += 256) {   // per-head gram entries
        const int h = idx / 24, u = idx - h * 24;
        float s = 0.f;
        if (u < 16) {
            const int i = u >> 2, j = u & 3;
            const float* tq = &TQ[(4*h + i) * 65];
            const float* wk = &Wl[(64 + 4*h + j) * 65];
            for (int c = 0; c < 64; ++c) s += tq[c] * wk[c];
            qkb[h * 16 + u] = s;
        } else if (u < 20) {
            const int i = u - 16;
            const float* tq = &TQ[(4*h + i) * 65];
            const float* wq = &Wl[(4*h + i) * 65];
            for (int c = 0; c < 64; ++c) s += tq[c] * wq[c];
            qqb[h * 4 + i] = s;
        } else {
            const int j = u - 20;
            const float* tk = &TK[(4*h + j) * 65];
            const float* wk = &Wl[(64 + 4*h + j) * 65];
            for (int c = 0; c < 64; ++c) s += tk[c] * wk[c];
            kkb[h * 4 + j] = s;
        }
    }
    __syncthreads();

    if (t < 64) {                           // softmax over j (4-wide)
        const int h = t >> 2, i = t & 3;
        const float tp = temp[e * 16 + h];
        const float rq = 1.0f / fmaxf(sqrtf(qqb[h*4 + i]), 1e-12f);
        float lq[4];
        #pragma unroll
        for (int j = 0; j < 4; ++j) {
            float rk = 1.0f / fmaxf(sqrtf(kkb[h*4 + j]), 1e-12f);
            lq[j] = qkb[h*16 + i*4 + j] * rq * rk * tp;
        }
        float m = fmaxf(fmaxf(lq[0], lq[1]), fmaxf(lq[2], lq[3]));
        float ex[4]; float s = 0.f;
        #pragma unroll
        for (int j = 0; j < 4; ++j) { ex[j] = expf(lq[j] - m); s += ex[j]; }
        float inv = 1.0f / s;
        #pragma unroll
        for (int j = 0; j < 4; ++j) atl[h*16 + i*4 + j] = ex[j] * inv;
    }
    __syncthreads();

    // Mv[o][c] = sum_j attn[h(o)][o%4][j] * Wv[4h+j][c]
    float* mv = ws + OFF_MV + (size_t)blockIdx.x * 4096;
    for (int idx = t; idx < 4096; idx += 256) {
        const int o = idx >> 6, c = idx & 63;
        const int h = o >> 2, ii = o & 3;
        float s = 0.f;
        #pragma unroll
        for (int j = 0; j < 4; ++j)
            s += atl[h*16 + ii*4 + j] * Wl[(128 + 4*h + j) * 65 + c];
        mv[idx] = s;
    }
}

// ---------------------------------------------------------------------------
// Kernel 3: fold logit*proj*dw(tap)*Mv -> H[b][64][tap*64+c] bf16.
// grid 72 = 8 b x 9 taps, block 256. Zero when no expert active.
// ---------------------------------------------------------------------------
__global__ __launch_bounds__(256) void hbuild_kernel(const float* __restrict__ dw_w,
        const float* __restrict__ proj_w, float* __restrict__ ws) {
    __shared__ float Pl[64 * 65];
    __shared__ float Ml[64 * 65];
    const int t = threadIdx.x;
    const int b = blockIdx.x / 9, tap = blockIdx.x - b * 9;
    const int o = t >> 2, c4 = (t & 3) << 4;
    float s[16];
    #pragma unroll
    for (int i = 0; i < 16; ++i) s[i] = 0.f;
    for (int e = 0; e < 3; ++e) {
        const float lg = ws[OFF_LOGIT + b * 3 + e];
        __syncthreads();
        if (lg > 0.f) {
            for (int idx = t; idx < 4096; idx += 256) {
                const int oo = idx >> 6, mm = idx & 63;
                Pl[oo * 65 + mm] = proj_w[e * 4096 + idx] * dw_w[e * 576 + mm * 9 + tap] * lg;
                Ml[oo * 65 + mm] = ws[OFF_MV + (size_t)(e * 8 + b) * 4096 + idx];
            }
            __syncthreads();
            for (int m = 0; m < 64; ++m) {
                const float wv = Pl[o * 65 + m];
                const float* mr = &Ml[m * 65 + c4];
                #pragma unroll
                for (int i = 0; i < 16; ++i) s[i] += wv * mr[i];
            }
        }
    }
    unsigned short* Hg = (unsigned short*)((char*)ws + OFF_H_BYTES);
    unsigned short* hrow = Hg + (size_t)(b * 64 + o) * 576 + tap * 64 + c4;
    #pragma unroll
    for (int i = 0; i < 16; ++i) hrow[i] = f2bf(s[i]);
}

// ---------------------------------------------------------------------------
// Kernel 4: implicit-GEMM 3x3 conv:  out[b] = sum_tap H[b,tap] @ shift(x[b])
// grid 256 = 8 b x 16 ytiles x 2 xtiles, block 512 (8 waves).
// Staging from x_t: contiguous 1KB/instr b128 loads, conflict-free LDS writes.
// ---------------------------------------------------------------------------
__global__ __launch_bounds__(512, 2) void conv_kernel(const float* __restrict__ ws_ro,
        float* __restrict__ out) {
    __shared__ unsigned short xl[10 * XP];     // 84480 B
    __shared__ unsigned short hl[64 * HP];     // 74752 B
    const int t = threadIdx.x;
    const int w = t >> 6, l = t & 63;
    const int bx = blockIdx.x;
    const int b = bx >> 5;
    const int tile = bx & 31;
    const int ty = tile >> 1, tx = tile & 1;
    const int y0 = ty << 3, x0 = tx << 6;
    const unsigned short* xt = (const unsigned short*)((const char*)ws_ro + OFF_XT_BYTES)
                             + ((size_t)b << 20);

    // ---- stage x halo from x_t ----
    for (int rr = w; rr < 10; rr += 8) {
        const int gy = y0 - 1 + rr;
        const bool yok = ((unsigned)gy < 128u);
        for (int u = l; u < 528; u += 64) {
            const int col = u >> 3, j = u & 7;
            const int gx = x0 - 1 + col;
            bf16x8 v = {0, 0, 0, 0, 0, 0, 0, 0};
            if (yok && ((unsigned)gx < 128u))
                v = *(const bf16x8*)&xt[((size_t)((gy << 7) + gx) << 6) + (j << 3)];
            *(bf16x8*)&xl[rr * XP + (col << 6) + ((j ^ (col & 7)) << 3)] = v;
        }
    }
    // ---- stage H[b]: wave w stages rows 8w..8w+7, contiguous per row ----
    {
        const unsigned short* hg = (const unsigned short*)((const char*)ws_ro + OFF_H_BYTES)
                                 + (size_t)b * 36864;
        #pragma unroll
        for (int r = 0; r < 8; ++r) {
            const int row = (w << 3) + r;
            for (int u = l; u < 72; u += 64)
                *(bf16x8*)&hl[row * HP + (u << 3)] = *(const bf16x8*)&hg[row * 576 + (u << 3)];
        }
    }
    __syncthreads();

    f32x4 acc[4][4];
    const f32x4 fz = {0.f, 0.f, 0.f, 0.f};
    #pragma unroll
    for (int mi = 0; mi < 4; ++mi)
        #pragma unroll
        for (int f = 0; f < 4; ++f) acc[mi][f] = fz;

    const int aoff = (l & 15) * HP + (l >> 4) * 8;
    const int bcol = (l & 15) * 64;
    int su8[3][2];                         // swizzled unit offset per (dx+1, s)
    #pragma unroll
    for (int dxi = 0; dxi < 3; ++dxi)
        #pragma unroll
        for (int s = 0; s < 2; ++s)
            su8[dxi][s] = ((s * 4 + (l >> 4)) ^ (((l & 15) + dxi) & 7)) << 3;

    #pragma unroll
    for (int tap = 0; tap < 9; ++tap) {
        const int dy = tap / 3 - 1;
        const int dxi = tap % 3;           // dx + 1
        const int hr = w + 1 + dy;
        #pragma unroll
        for (int s = 0; s < 2; ++s) {
            const int k0 = tap * 64 + s * 32;
            bf16x8 af[4], bfr[4];
            #pragma unroll
            for (int mi = 0; mi < 4; ++mi)
                af[mi] = *(const bf16x8*)&hl[mi * 16 * HP + k0 + aoff];
            #pragma unroll
            for (int f = 0; f < 4; ++f)
                bfr[f] = *(const bf16x8*)&xl[hr * XP + (f * 16 + dxi) * 64 + bcol + su8[dxi][s]];
            #pragma unroll
            for (int mi = 0; mi < 4; ++mi)
                #pragma unroll
                for (int f = 0; f < 4; ++f)
                    acc[mi][f] = __builtin_amdgcn_mfma_f32_16x16x32_bf16(af[mi], bfr[f], acc[mi][f], 0, 0, 0);
        }
    }

    // ---- epilogue: D layout col=lane&15 (pixel), row=(lane>>4)*4+j (channel)
    const int gy = y0 + w;
    float* ob = out + ((size_t)b << 20) + (gy << 7) + x0;
    const int orow = (l >> 4) << 2;
    const int ocol = l & 15;
    #pragma unroll
    for (int mi = 0; mi < 4; ++mi)
        #pragma unroll
        for (int f = 0; f < 4; ++f)
            #pragma unroll
            for (int j = 0; j < 4; ++j)
                ob[((size_t)(mi * 16 + orow + j) << 14) + f * 16 + ocol] = acc[mi][f][j];
}

// ---------------------------------------------------------------------------
extern "C" void kernel_launch(void* const* d_in, const int* in_sizes, int n_in,
                              void* d_out, int out_size, void* d_ws, size_t ws_size,
                              hipStream_t stream) {
    const float* x      = (const float*)d_in[0];
    const float* hidden = (const float*)d_in[1];
    const float* qkv_w  = (const float*)d_in[2];
    const float* dw_w   = (const float*)d_in[3];
    const float* proj_w = (const float*)d_in[4];
    const float* temp   = (const float*)d_in[5];
    const float* r1w    = (const float*)d_in[6];
    const float* r1b    = (const float*)d_in[7];
    const float* r3w    = (const float*)d_in[8];
    const float* r3b    = (const float*)d_in[9];
    float* out = (float*)d_out;
    float* ws  = (float*)d_ws;

    // no memset needed: all ws regions are fully overwritten before use
    cov_kernel   <<<dim3(256), dim3(256), 0, stream>>>(x, ws);
    attn_kernel  <<<dim3(24),  dim3(256), 0, stream>>>(qkv_w, temp, hidden,
                                                       r1w, r1b, r3w, r3b, ws, out);
    hbuild_kernel<<<dim3(72),  dim3(256), 0, stream>>>(dw_w, proj_w, ws);
    conv_kernel  <<<dim3(256), dim3(512), 0, stream>>>(ws, out);
}